// Round 12
// baseline (597.855 us; speedup 1.0000x reference)
//
#include <hip/hip_runtime.h>
#include <math.h>

#define B_ROWS 8192
#define C_COLS 4096
#define D_DIM  1024
#define EPSN   1e-12f

typedef float v4f __attribute__((ext_vector_type(4)));
typedef short v8s __attribute__((ext_vector_type(8)));

__device__ __forceinline__ unsigned short bf16_rtn(float x) {
    unsigned int u = __float_as_uint(x);
    u += 0x7fffu + ((u >> 16) & 1u);
    return (unsigned short)(u >> 16);
}

// strict total order (value desc, index asc) == first-occurrence argmax
__device__ __forceinline__ bool better_vi(float v, int i, float V, int I) {
    return (v > V) || (v == V && i < I);
}

// ---------------------------------------------------------------------------
// Kernel 1: wave-per-row normalize + bf16 convert. (R3-proven) + zeroing of
// the 32 per-band completion counters used by the fused finalize (stream
// order guarantees this completes before simmax starts; re-done every launch
// so reset()-poisoned workspace is always re-armed).
// ---------------------------------------------------------------------------
__global__ __launch_bounds__(256) void prep_kernel(
    const float* __restrict__ emb, const float* __restrict__ cen,
    unsigned short* __restrict__ Ah, unsigned short* __restrict__ Bh,
    float* __restrict__ inv_a, float* __restrict__ inv_b,
    int* __restrict__ band_ctr)
{
    if (blockIdx.x == 0 && threadIdx.x < 32) band_ctr[threadIdx.x] = 0;

    const int lane = threadIdx.x & 63;
    const int wid  = blockIdx.x * 4 + (threadIdx.x >> 6);
    const float* src; unsigned short* dst; float* invp; int r;
    if (wid < B_ROWS) { src = emb; r = wid;          dst = Ah; invp = inv_a; }
    else              { src = cen; r = wid - B_ROWS; dst = Bh; invp = inv_b; }

    const float* rp = src + (size_t)r * D_DIM;
    float4 v[4];
    float ss = 0.0f;
    #pragma unroll
    for (int j = 0; j < 4; ++j) {
        v[j] = *(const float4*)(rp + (j * 64 + lane) * 4);
        ss += v[j].x * v[j].x + v[j].y * v[j].y + v[j].z * v[j].z + v[j].w * v[j].w;
    }
    #pragma unroll
    for (int off = 1; off < 64; off <<= 1) ss += __shfl_xor(ss, off, 64);

    const float iv = 1.0f / fmaxf(sqrtf(ss), EPSN);
    if (lane == 0) invp[r] = iv;

    unsigned short* dp = dst + (size_t)r * D_DIM;
    #pragma unroll
    for (int j = 0; j < 4; ++j) {
        ushort4 H;
        H.x = bf16_rtn(v[j].x * iv);
        H.y = bf16_rtn(v[j].y * iv);
        H.z = bf16_rtn(v[j].z * iv);
        H.w = bf16_rtn(v[j].w * iv);
        *(ushort4*)(dp + (j * 64 + lane) * 4) = H;
    }
}

// ---------------------------------------------------------------------------
// Kernel 2 (R17): R16 body (best measured: 94.3 us simmax, banded XCD
// swizzle, 0 conflicts, 2 blk/CU) + FUSED finalize via per-band last-block.
// Band bx's 32 by-blocks produce all 64 p-chunks for rows [bx*256,+256).
// Each block: p-writes -> __threadfence -> __syncthreads -> tid0 atomicAdd
// (device-scope, m20) on band_ctr[bx]. The 32nd arriver re-fences and runs
// the R3/R5-proven finalize body for the band's 256 rows (8 waves x 32
// rows). No spin (no waiting -> no deadlock); early bands' finalize overlaps
// other bands' GEMM; one kernel boundary eliminated. launch_bounds(512,4)
// pins 16 waves/CU so the tail can't cost simmax its occupancy (tail
// pressure spills into the then-dead AGPRs). Finalize math verbatim ->
// bit-identical output.
// ---------------------------------------------------------------------------
#define GLD16(gp, lp) \
    __builtin_amdgcn_global_load_lds( \
        (const __attribute__((address_space(1))) void*)(gp), \
        (__attribute__((address_space(3))) void*)(lp), 16, 0, 0)

__global__ __launch_bounds__(512, 4) void simmax_kernel(
    const unsigned short* __restrict__ Ahg, const unsigned short* __restrict__ Bhg,
    const float* __restrict__ emb, const float* __restrict__ cen,
    const float* __restrict__ inv_a, const float* __restrict__ inv_b,
    float* __restrict__ p1v, int* __restrict__ p1i,
    float* __restrict__ p2v, int* __restrict__ p2i,
    float* __restrict__ out, int* __restrict__ band_ctr)
{
    // A(256x64) 16384 shorts | B(128x64) 8192 shorts = 48 KB, single buffer
    __shared__ unsigned short lds[24576];
    __shared__ int last_flag;

    const int tid    = threadIdx.x;          // 0..511
    const int L      = tid & 63;
    const int w      = tid >> 6;             // 0..7
    const int lane15 = L & 15;
    const int quad   = L >> 4;
    const int wr     = w >> 1;               // 0..3 (M quarter)
    const int wc     = w & 1;                // 0..1 (N half)

    // XCD-banded bijective swizzle: 1024 blocks, hw xcd = bid&7.
    const int bid = blockIdx.x;
    const int xc  = bid & 7;                 // XCD id
    const int s   = bid >> 3;                // 0..127
    const int bx  = xc * 4 + (s & 3);        // 0..31 (M tile / band)
    const int by  = s >> 2;                  // 0..31 (N tile)
    const int row0 = bx * 256;
    const int c0   = by * 128;

    // staging: each issue covers 64 rows (8 rows/wave, 1 KB/wave); lane L
    // writes row base+(tid>>3), phys granule L&7 <- logical granule scol
    const int scol = (tid & 7) ^ ((tid >> 3) & 7);
    const unsigned short* aB = Ahg + (size_t)(row0 + (tid >> 3)) * D_DIM + scol * 8;
    const unsigned short* bB = Bhg + (size_t)(c0   + (tid >> 3)) * D_DIM + scol * 8;
    const int wofs = w * 512;                // shorts: (w*8 rows) * 64

    // 6 issues/thread per K-tile: A rows {0,64,128,192}, B rows {0,64}
#define STAGE_ALL(kb) do { \
    GLD16(aB + (kb),           &lds[0     + wofs]); \
    GLD16(aB + 65536  + (kb),  &lds[4096  + wofs]); \
    GLD16(aB + 131072 + (kb),  &lds[8192  + wofs]); \
    GLD16(aB + 196608 + (kb),  &lds[12288 + wofs]); \
    GLD16(bB + (kb),           &lds[16384 + wofs]); \
    GLD16(bB + 65536  + (kb),  &lds[20480 + wofs]); \
} while (0)

    v4f acc[4][4];
    #pragma unroll
    for (int mt = 0; mt < 4; ++mt)
        #pragma unroll
        for (int nt = 0; nt < 4; ++nt) acc[mt][nt] = (v4f)0.0f;

    // fragment geometry: rows * 64 shorts (128-B rows = full bank wrap)
    int rAo[4], rBo[4];
    #pragma unroll
    for (int t = 0; t < 4; ++t) {
        rAo[t] = (wr * 64 + t * 16 + lane15) * 64;
        rBo[t] = 16384 + (wc * 64 + t * 16 + lane15) * 64;
    }
    const int s7 = lane15 & 7;
    const int cq[2] = { (quad ^ s7) * 8, ((4 + quad) ^ s7) * 8 };  // shorts

    for (int kc = 0; kc < D_DIM / 64; ++kc) {
        STAGE_ALL(kc * 64);
        __syncthreads();                     // staging resident (vmcnt drained)

        #pragma unroll
        for (int h = 0; h < 2; ++h) {
            v8s fah[4], fbh[4];
            #pragma unroll
            for (int t = 0; t < 4; ++t) {
                fah[t] = *(const v8s*)&lds[rAo[t] + cq[h]];
                fbh[t] = *(const v8s*)&lds[rBo[t] + cq[h]];
            }
            #pragma unroll
            for (int mt = 0; mt < 4; ++mt)
                #pragma unroll
                for (int nt = 0; nt < 4; ++nt)
                    acc[mt][nt] = __builtin_amdgcn_mfma_f32_16x16x32_bf16(
                        fah[mt], fbh[nt], acc[mt][nt], 0, 0, 0);
        }
        __syncthreads();                     // all reads done before overwrite
    }

    // fused top-2 epilogue (R6/R10-proven). C/D: col = lane&15, row = quad*4+reg.
    const int pc = by * 2 + wc;              // 0..63 column chunk id (64 cols)
    #pragma unroll
    for (int mt = 0; mt < 4; ++mt) {
        #pragma unroll
        for (int r = 0; r < 4; ++r) {
            float a1v = acc[mt][0][r];
            int   a1i = c0 + wc * 64 + 0 * 16 + lane15;
            float a2v = -1e30f;
            int   a2i = 0x7fffffff;
            #pragma unroll
            for (int nt = 1; nt < 4; ++nt) {
                float v  = acc[mt][nt][r];
                int   ci = c0 + wc * 64 + nt * 16 + lane15;
                if (better_vi(v, ci, a1v, a1i))      { a2v = a1v; a2i = a1i; a1v = v; a1i = ci; }
                else if (better_vi(v, ci, a2v, a2i)) { a2v = v;   a2i = ci; }
            }
            #pragma unroll
            for (int off = 8; off; off >>= 1) {
                float b1v = __shfl_down(a1v, off, 64); int b1i = __shfl_down(a1i, off, 64);
                float b2v = __shfl_down(a2v, off, 64); int b2i = __shfl_down(a2i, off, 64);
                if (better_vi(b1v, b1i, a1v, a1i)) {
                    if (better_vi(a1v, a1i, b2v, b2i)) { a2v = a1v; a2i = a1i; }
                    else                               { a2v = b2v; a2i = b2i; }
                    a1v = b1v; a1i = b1i;
                } else if (better_vi(b1v, b1i, a2v, a2i)) {
                    a2v = b1v; a2i = b1i;
                }
            }
            if (lane15 == 0) {
                int rg = row0 + wr * 64 + mt * 16 + quad * 4 + r;
                size_t ix = (size_t)rg * 64 + pc;  // [row][chunk] layout
                p1v[ix] = a1v; p1i[ix] = a1i;
                p2v[ix] = a2v; p2i[ix] = a2i;
            }
        }
    }

    // ---- fused finalize: last arriver of band bx finalizes its 256 rows ----
    __threadfence();                         // release: p-writes device-visible
    __syncthreads();                         // all threads' fences done
    if (tid == 0) {
        int old = atomicAdd(band_ctr + bx, 1);   // device-scope (m20)
        last_flag = (old == 31);
    }
    __syncthreads();
    if (!last_flag) return;
    __threadfence();                         // acquire: peers' p-writes visible

    for (int rr = 0; rr < 32; ++rr) {
        const int row = row0 + w * 32 + rr;
        const size_t base = (size_t)row * 64 + L;

        float v[4]; int ix[4];
        v[0] = p1v[base]; ix[0] = p1i[base];
        v[1] = p2v[base]; ix[1] = p2i[base];
        v[2] = -1e30f;    ix[2] = 0x7ffffffe;
        v[3] = -1e30f;    ix[3] = 0x7fffffff;

        #pragma unroll
        for (int off = 1; off < 64; off <<= 1) {
            float ov[4]; int oi[4];
            #pragma unroll
            for (int k = 0; k < 4; ++k) {
                ov[k] = __shfl_xor(v[k],  off, 64);
                oi[k] = __shfl_xor(ix[k], off, 64);
            }
            #pragma unroll
            for (int k = 0; k < 4; ++k) {
                float bv = ov[k]; int bi = oi[k];
                bool b0 = better_vi(bv, bi, v[0], ix[0]);
                bool b1 = better_vi(bv, bi, v[1], ix[1]);
                bool b2 = better_vi(bv, bi, v[2], ix[2]);
                bool b3 = better_vi(bv, bi, v[3], ix[3]);
                float nv3 = b2 ? v[2] : (b3 ? bv : v[3]); int ni3 = b2 ? ix[2] : (b3 ? bi : ix[3]);
                float nv2 = b1 ? v[1] : (b2 ? bv : v[2]); int ni2 = b1 ? ix[1] : (b2 ? bi : ix[2]);
                float nv1 = b0 ? v[0] : (b1 ? bv : v[1]); int ni1 = b0 ? ix[0] : (b1 ? bi : ix[1]);
                float nv0 = b0 ? bv   : v[0];             int ni0 = b0 ? bi    : ix[0];
                v[0] = nv0; ix[0] = ni0; v[1] = nv1; ix[1] = ni1;
                v[2] = nv2; ix[2] = ni2; v[3] = nv3; ix[3] = ni3;
            }
        }

        const float* er  = emb + (size_t)row * D_DIM;
        const float* cr0 = cen + (size_t)ix[0] * D_DIM;
        const float* cr1 = cen + (size_t)ix[1] * D_DIM;
        const float* cr2 = cen + (size_t)ix[2] * D_DIM;
        const float* cr3 = cen + (size_t)ix[3] * D_DIM;

        float d[4] = { 0.0f, 0.0f, 0.0f, 0.0f };
        #pragma unroll
        for (int j = 0; j < 4; ++j) {
            int e = (j * 64 + L) * 4;
            float4 ev = *(const float4*)(er  + e);
            float4 c0 = *(const float4*)(cr0 + e);
            float4 c1 = *(const float4*)(cr1 + e);
            float4 c2 = *(const float4*)(cr2 + e);
            float4 c3 = *(const float4*)(cr3 + e);
            d[0] += ev.x * c0.x + ev.y * c0.y + ev.z * c0.z + ev.w * c0.w;
            d[1] += ev.x * c1.x + ev.y * c1.y + ev.z * c1.z + ev.w * c1.w;
            d[2] += ev.x * c2.x + ev.y * c2.y + ev.z * c2.z + ev.w * c2.w;
            d[3] += ev.x * c3.x + ev.y * c3.y + ev.z * c3.z + ev.w * c3.w;
        }
        #pragma unroll
        for (int off = 1; off < 64; off <<= 1) {
            #pragma unroll
            for (int c = 0; c < 4; ++c) d[c] += __shfl_xor(d[c], off, 64);
        }

        if (L == 0) {
            const float ia = inv_a[row];
            float m = -1e30f; int ci = 0x7fffffff;
            #pragma unroll
            for (int c = 0; c < 4; ++c) {
                float sc = d[c] * ia * inv_b[ix[c]];
                if (better_vi(sc, ix[c], m, ci)) { m = sc; ci = ix[c]; }
            }
            if (m <= 0.0f) ci = 0;  // all sims clip to 0 -> argmax = 0
            float ms = fminf(fmaxf(m, 0.0f), 1.0f);
            out[row]          = fminf(fmaxf(sqrtf(1.0f - ms), 0.0f), 1.0f);
            out[B_ROWS + row] = (float)ci;
        }
    }
}

// ---------------------------------------------------------------------------
// Workspace (~33 MB): Ah 16MB | Bh 8MB | inv_a 32KB | inv_b 16KB |
//     p1v/p1i/p2v/p2i 2MB each ([row][chunk] layout) | band_ctr 128 B
// ---------------------------------------------------------------------------
extern "C" void kernel_launch(void* const* d_in, const int* in_sizes, int n_in,
                              void* d_out, int out_size, void* d_ws, size_t ws_size,
                              hipStream_t stream)
{
    const float* emb = (const float*)d_in[0];
    const float* cen = (const float*)d_in[1];
    float* out = (float*)d_out;

    unsigned short* Ahp = (unsigned short*)d_ws;
    unsigned short* Bhp = Ahp + (size_t)B_ROWS * D_DIM;
    float* inv_a = (float*)(Bhp + (size_t)C_COLS * D_DIM);
    float* inv_b = inv_a + B_ROWS;
    float* p1v   = inv_b + C_COLS;
    int*   p1i   = (int*)(p1v + (size_t)64 * B_ROWS);
    float* p2v   = (float*)(p1i + (size_t)64 * B_ROWS);
    int*   p2i   = (int*)(p2v + (size_t)64 * B_ROWS);
    int*   band_ctr = p2i + (size_t)64 * B_ROWS;

    prep_kernel<<<(B_ROWS + C_COLS) / 4, 256, 0, stream>>>(
        emb, cen, Ahp, Bhp, inv_a, inv_b, band_ctr);

    simmax_kernel<<<dim3(1024), 512, 0, stream>>>(
        Ahp, Bhp, emb, cen, inv_a, inv_b, p1v, p1i, p2v, p2i, out, band_ctr);
}

// Round 13
// 205.381 us; speedup vs baseline: 2.9110x; 2.9110x over previous
//
#include <hip/hip_runtime.h>
#include <math.h>

#define B_ROWS 8192
#define C_COLS 4096
#define D_DIM  1024
#define EPSN   1e-12f

typedef float v4f __attribute__((ext_vector_type(4)));
typedef short v8s __attribute__((ext_vector_type(8)));

__device__ __forceinline__ unsigned short bf16_rtn(float x) {
    unsigned int u = __float_as_uint(x);
    u += 0x7fffu + ((u >> 16) & 1u);
    return (unsigned short)(u >> 16);
}

// strict total order (value desc, index asc) == first-occurrence argmax
__device__ __forceinline__ bool better_vi(float v, int i, float V, int I) {
    return (v > V) || (v == V && i < I);
}

// ---------------------------------------------------------------------------
// Kernel 1: wave-per-row normalize + bf16 convert. (R3-proven, unchanged)
// ---------------------------------------------------------------------------
__global__ __launch_bounds__(256) void prep_kernel(
    const float* __restrict__ emb, const float* __restrict__ cen,
    unsigned short* __restrict__ Ah, unsigned short* __restrict__ Bh,
    float* __restrict__ inv_a, float* __restrict__ inv_b)
{
    const int lane = threadIdx.x & 63;
    const int wid  = blockIdx.x * 4 + (threadIdx.x >> 6);
    const float* src; unsigned short* dst; float* invp; int r;
    if (wid < B_ROWS) { src = emb; r = wid;          dst = Ah; invp = inv_a; }
    else              { src = cen; r = wid - B_ROWS; dst = Bh; invp = inv_b; }

    const float* rp = src + (size_t)r * D_DIM;
    float4 v[4];
    float ss = 0.0f;
    #pragma unroll
    for (int j = 0; j < 4; ++j) {
        v[j] = *(const float4*)(rp + (j * 64 + lane) * 4);
        ss += v[j].x * v[j].x + v[j].y * v[j].y + v[j].z * v[j].z + v[j].w * v[j].w;
    }
    #pragma unroll
    for (int off = 1; off < 64; off <<= 1) ss += __shfl_xor(ss, off, 64);

    const float iv = 1.0f / fmaxf(sqrtf(ss), EPSN);
    if (lane == 0) invp[r] = iv;

    unsigned short* dp = dst + (size_t)r * D_DIM;
    #pragma unroll
    for (int j = 0; j < 4; ++j) {
        ushort4 H;
        H.x = bf16_rtn(v[j].x * iv);
        H.y = bf16_rtn(v[j].y * iv);
        H.z = bf16_rtn(v[j].z * iv);
        H.w = bf16_rtn(v[j].w * iv);
        *(ushort4*)(dp + (j * 64 + lane) * 4) = H;
    }
}

// ---------------------------------------------------------------------------
// Kernel 2 (R18): R16 body + A-only double-buffer with counted vmcnt at FULL
// occupancy. R17's fused finalize REVERTED (device fences invalidate the
// non-coherent L2s -> FETCH 130 MB, 5x regression). The untested matrix cell:
// counted-vmcnt was only ever run at 1 blk/CU (R11) or with a broken bank
// layout (R14). Here: A dbuf 2x32 KB + B single 16 KB = 80 KB exactly ->
// 2 blk/CU preserved (163840 B = the full 160 KiB; observed LDS_Block_Size
// values are exact, no padding). Proven 128-B-row g^(row&7) swizzle kept for
// BOTH operands (rows stay 64 shorts). Per-K-tile per-wave FIFO:
//   [A-cur(4) | B-cur(2) | A-next(4)] ; vmcnt(4) retires A-cur+B-cur and
// leaves A-next (2/3 of staged bytes) a FULL K-tile of latency cover.
// Raw s_barrier pair; trailing barrier needs no vmcnt (next B staging is
// issued only after it -> write-after-read on B ordered). kc=15 drains to 0.
// Fragment geometry, K-order, epilogue = R16 verbatim -> bit-identical.
// ---------------------------------------------------------------------------
#define GLD16(gp, lp) \
    __builtin_amdgcn_global_load_lds( \
        (const __attribute__((address_space(1))) void*)(gp), \
        (__attribute__((address_space(3))) void*)(lp), 16, 0, 0)

__global__ __launch_bounds__(512, 4) void simmax_kernel(
    const unsigned short* __restrict__ Ahg, const unsigned short* __restrict__ Bhg,
    float* __restrict__ p1v, int* __restrict__ p1i,
    float* __restrict__ p2v, int* __restrict__ p2i)
{
    // A buf0: 0..16383 | A buf1: 16384..32767 | B: 32768..40959  (shorts)
    // = 81920 B exactly; 2 blocks x 81920 = 163840 B = 160 KiB/CU.
    __shared__ unsigned short lds[40960];

    const int tid    = threadIdx.x;          // 0..511
    const int L      = tid & 63;
    const int w      = tid >> 6;             // 0..7
    const int lane15 = L & 15;
    const int quad   = L >> 4;
    const int wr     = w >> 1;               // 0..3 (M quarter)
    const int wc     = w & 1;                // 0..1 (N half)

    // XCD-banded bijective swizzle (R16-proven, +2.3%): hw xcd = bid&7.
    const int bid = blockIdx.x;
    const int xc  = bid & 7;                 // XCD id
    const int s   = bid >> 3;                // 0..127
    const int bx  = xc * 4 + (s & 3);        // 0..31 (M tile)
    const int by  = s >> 2;                  // 0..31 (N tile)
    const int row0 = bx * 256;
    const int c0   = by * 128;

    // staging: each issue covers 64 rows (8 rows/wave, 1 KB/wave); lane L
    // writes row base+(tid>>3), phys granule L&7 <- logical granule scol
    const int scol = (tid & 7) ^ ((tid >> 3) & 7);
    const unsigned short* aB = Ahg + (size_t)(row0 + (tid >> 3)) * D_DIM + scol * 8;
    const unsigned short* bB = Bhg + (size_t)(c0   + (tid >> 3)) * D_DIM + scol * 8;
    const int wofs = w * 512;                // shorts: (w*8 rows) * 64

#define STAGE_A(ab, kb) do { \
    GLD16(aB + (kb),           &lds[(ab) + 0     + wofs]); \
    GLD16(aB + 65536  + (kb),  &lds[(ab) + 4096  + wofs]); \
    GLD16(aB + 131072 + (kb),  &lds[(ab) + 8192  + wofs]); \
    GLD16(aB + 196608 + (kb),  &lds[(ab) + 12288 + wofs]); \
} while (0)
#define STAGE_B(kb) do { \
    GLD16(bB + (kb),           &lds[32768 + wofs]); \
    GLD16(bB + 65536  + (kb),  &lds[36864 + wofs]); \
} while (0)

    v4f acc[4][4];
    #pragma unroll
    for (int mt = 0; mt < 4; ++mt)
        #pragma unroll
        for (int nt = 0; nt < 4; ++nt) acc[mt][nt] = (v4f)0.0f;

    // fragment geometry: rows * 64 shorts (128-B rows = full bank wrap)
    int rAo[4], rBo[4];
    #pragma unroll
    for (int t = 0; t < 4; ++t) {
        rAo[t] = (wr * 64 + t * 16 + lane15) * 64;           // + abase
        rBo[t] = 32768 + (wc * 64 + t * 16 + lane15) * 64;
    }
    const int s7 = lane15 & 7;
    const int cq[2] = { (quad ^ s7) * 8, ((4 + quad) ^ s7) * 8 };  // shorts

    // prologue: A tile 0 into buf0 (4 loads in flight)
    STAGE_A(0, 0);

    int abase = 0;
    for (int kc = 0; kc < 16; ++kc) {
        const int kb = kc * 64;
        STAGE_B(kb);                                   // B for THIS tile
        if (kc < 15) {
            STAGE_A(abase ^ 16384, kb + 64);           // A for NEXT tile
            asm volatile("s_waitcnt vmcnt(4)" ::: "memory");  // A-cur+B done
        } else {
            asm volatile("s_waitcnt vmcnt(0)" ::: "memory");
        }
        __builtin_amdgcn_s_barrier();                  // all waves' staging in
        __builtin_amdgcn_sched_barrier(0);

        #pragma unroll
        for (int h = 0; h < 2; ++h) {
            v8s fah[4], fbh[4];
            #pragma unroll
            for (int t = 0; t < 4; ++t) {
                fah[t] = *(const v8s*)&lds[abase + rAo[t] + cq[h]];
                fbh[t] = *(const v8s*)&lds[rBo[t] + cq[h]];
            }
            #pragma unroll
            for (int mt = 0; mt < 4; ++mt)
                #pragma unroll
                for (int nt = 0; nt < 4; ++nt)
                    acc[mt][nt] = __builtin_amdgcn_mfma_f32_16x16x32_bf16(
                        fah[mt], fbh[nt], acc[mt][nt], 0, 0, 0);
        }
        __builtin_amdgcn_s_barrier();                  // B reads done before
        abase ^= 16384;                                // next B staging
    }

    // fused top-2 epilogue (R6/R10/R16-proven). C/D: col=lane&15, row=quad*4+reg.
    const int pc = by * 2 + wc;              // 0..63 column chunk id (64 cols)
    #pragma unroll
    for (int mt = 0; mt < 4; ++mt) {
        #pragma unroll
        for (int r = 0; r < 4; ++r) {
            float a1v = acc[mt][0][r];
            int   a1i = c0 + wc * 64 + 0 * 16 + lane15;
            float a2v = -1e30f;
            int   a2i = 0x7fffffff;
            #pragma unroll
            for (int nt = 1; nt < 4; ++nt) {
                float v  = acc[mt][nt][r];
                int   ci = c0 + wc * 64 + nt * 16 + lane15;
                if (better_vi(v, ci, a1v, a1i))      { a2v = a1v; a2i = a1i; a1v = v; a1i = ci; }
                else if (better_vi(v, ci, a2v, a2i)) { a2v = v;   a2i = ci; }
            }
            #pragma unroll
            for (int off = 8; off; off >>= 1) {
                float b1v = __shfl_down(a1v, off, 64); int b1i = __shfl_down(a1i, off, 64);
                float b2v = __shfl_down(a2v, off, 64); int b2i = __shfl_down(a2i, off, 64);
                if (better_vi(b1v, b1i, a1v, a1i)) {
                    if (better_vi(a1v, a1i, b2v, b2i)) { a2v = a1v; a2i = a1i; }
                    else                               { a2v = b2v; a2i = b2i; }
                    a1v = b1v; a1i = b1i;
                } else if (better_vi(b1v, b1i, a2v, a2i)) {
                    a2v = b1v; a2i = b1i;
                }
            }
            if (lane15 == 0) {
                int rg = row0 + wr * 64 + mt * 16 + quad * 4 + r;
                size_t ix = (size_t)rg * 64 + pc;  // [row][chunk] layout
                p1v[ix] = a1v; p1i[ix] = a1i;
                p2v[ix] = a2v; p2i[ix] = a2i;
            }
        }
    }
}

// ---------------------------------------------------------------------------
// Kernel 3: R3/R5-proven finalize (wave per row, 4 rows/block, j-outer MLP
// rescore). Unchanged.
// ---------------------------------------------------------------------------
__global__ __launch_bounds__(256) void finalize_kernel(
    const float* __restrict__ emb, const float* __restrict__ cen,
    const float* __restrict__ inv_a, const float* __restrict__ inv_b,
    const float* __restrict__ p1v, const int* __restrict__ p1i,
    const float* __restrict__ p2v, const int* __restrict__ p2i,
    float* __restrict__ out)
{
    const int lane = threadIdx.x & 63;
    const int row  = blockIdx.x * 4 + (threadIdx.x >> 6);
    const size_t base = (size_t)row * 64 + lane;

    float v[4]; int ix[4];
    v[0] = p1v[base]; ix[0] = p1i[base];
    v[1] = p2v[base]; ix[1] = p2i[base];
    v[2] = -1e30f;    ix[2] = 0x7ffffffe;
    v[3] = -1e30f;    ix[3] = 0x7fffffff;

    #pragma unroll
    for (int off = 1; off < 64; off <<= 1) {
        float ov[4]; int oi[4];
        #pragma unroll
        for (int k = 0; k < 4; ++k) {
            ov[k] = __shfl_xor(v[k],  off, 64);
            oi[k] = __shfl_xor(ix[k], off, 64);
        }
        #pragma unroll
        for (int k = 0; k < 4; ++k) {
            float bv = ov[k]; int bi = oi[k];
            bool b0 = better_vi(bv, bi, v[0], ix[0]);
            bool b1 = better_vi(bv, bi, v[1], ix[1]);
            bool b2 = better_vi(bv, bi, v[2], ix[2]);
            bool b3 = better_vi(bv, bi, v[3], ix[3]);
            float nv3 = b2 ? v[2] : (b3 ? bv : v[3]); int ni3 = b2 ? ix[2] : (b3 ? bi : ix[3]);
            float nv2 = b1 ? v[1] : (b2 ? bv : v[2]); int ni2 = b1 ? ix[1] : (b2 ? bi : ix[2]);
            float nv1 = b0 ? v[0] : (b1 ? bv : v[1]); int ni1 = b0 ? ix[0] : (b1 ? bi : ix[1]);
            float nv0 = b0 ? bv   : v[0];             int ni0 = b0 ? bi    : ix[0];
            v[0] = nv0; ix[0] = ni0; v[1] = nv1; ix[1] = ni1;
            v[2] = nv2; ix[2] = ni2; v[3] = nv3; ix[3] = ni3;
        }
    }

    const float* er = emb + (size_t)row * D_DIM;
    const float* cr0 = cen + (size_t)ix[0] * D_DIM;
    const float* cr1 = cen + (size_t)ix[1] * D_DIM;
    const float* cr2 = cen + (size_t)ix[2] * D_DIM;
    const float* cr3 = cen + (size_t)ix[3] * D_DIM;

    float d[4] = { 0.0f, 0.0f, 0.0f, 0.0f };
    #pragma unroll
    for (int j = 0; j < 4; ++j) {
        int e = (j * 64 + lane) * 4;
        float4 ev = *(const float4*)(er  + e);
        float4 c0 = *(const float4*)(cr0 + e);
        float4 c1 = *(const float4*)(cr1 + e);
        float4 c2 = *(const float4*)(cr2 + e);
        float4 c3 = *(const float4*)(cr3 + e);
        d[0] += ev.x * c0.x + ev.y * c0.y + ev.z * c0.z + ev.w * c0.w;
        d[1] += ev.x * c1.x + ev.y * c1.y + ev.z * c1.z + ev.w * c1.w;
        d[2] += ev.x * c2.x + ev.y * c2.y + ev.z * c2.z + ev.w * c2.w;
        d[3] += ev.x * c3.x + ev.y * c3.y + ev.z * c3.z + ev.w * c3.w;
    }
    #pragma unroll
    for (int off = 1; off < 64; off <<= 1) {
        #pragma unroll
        for (int c = 0; c < 4; ++c) d[c] += __shfl_xor(d[c], off, 64);
    }

    if (lane == 0) {
        const float ia = inv_a[row];
        float m = -1e30f; int ci = 0x7fffffff;
        #pragma unroll
        for (int c = 0; c < 4; ++c) {
            float s = d[c] * ia * inv_b[ix[c]];
            if (better_vi(s, ix[c], m, ci)) { m = s; ci = ix[c]; }
        }
        if (m <= 0.0f) ci = 0;  // all sims clip to 0 -> argmax = 0
        float ms = fminf(fmaxf(m, 0.0f), 1.0f);
        out[row]          = fminf(fmaxf(sqrtf(1.0f - ms), 0.0f), 1.0f);
        out[B_ROWS + row] = (float)ci;
    }
}

// ---------------------------------------------------------------------------
// Workspace (~33 MB): Ah 16MB | Bh 8MB | inv_a 32KB | inv_b 16KB |
//                     p1v/p1i/p2v/p2i 2MB each ([row][chunk] layout)
// ---------------------------------------------------------------------------
extern "C" void kernel_launch(void* const* d_in, const int* in_sizes, int n_in,
                              void* d_out, int out_size, void* d_ws, size_t ws_size,
                              hipStream_t stream)
{
    const float* emb = (const float*)d_in[0];
    const float* cen = (const float*)d_in[1];
    float* out = (float*)d_out;

    unsigned short* Ahp = (unsigned short*)d_ws;
    unsigned short* Bhp = Ahp + (size_t)B_ROWS * D_DIM;
    float* inv_a = (float*)(Bhp + (size_t)C_COLS * D_DIM);
    float* inv_b = inv_a + B_ROWS;
    float* p1v   = inv_b + C_COLS;
    int*   p1i   = (int*)(p1v + (size_t)64 * B_ROWS);
    float* p2v   = (float*)(p1i + (size_t)64 * B_ROWS);
    int*   p2i   = (int*)(p2v + (size_t)64 * B_ROWS);

    prep_kernel<<<(B_ROWS + C_COLS) / 4, 256, 0, stream>>>(emb, cen, Ahp, Bhp, inv_a, inv_b);

    simmax_kernel<<<dim3(1024), 512, 0, stream>>>(Ahp, Bhp, p1v, p1i, p2v, p2i);

    finalize_kernel<<<B_ROWS / 4, 256, 0, stream>>>(emb, cen, inv_a, inv_b,
                                                    p1v, p1i, p2v, p2i, out);
}